// Round 12
// baseline (1423.402 us; speedup 1.0000x reference)
//
#include <hip/hip_runtime.h>

#define N_ 16384
#define D_ 256
#define KSPLIT 2
#define KPER (N_ / KSPLIT)   // 8192
#define BK 64
#define BM 64
#define NT (KPER / BK)       // 128 K-tiles

typedef __attribute__((ext_vector_type(8))) short short8_t;    // 8 bf16
typedef __attribute__((ext_vector_type(4))) short short4_t;    // 4 bf16
typedef __attribute__((ext_vector_type(4))) float f32x4;
typedef __attribute__((ext_vector_type(4))) unsigned int u32x4;

// fp32 -> bf16 round-to-nearest-even (bit manip; no hip_bf16 struct overhead)
static __device__ __forceinline__ short f2bf(float f) {
  unsigned int u = __float_as_uint(f);
  u += 0x7fffu + ((u >> 16) & 1u);
  return (short)(u >> 16);
}

// Direct global->LDS copy, 16 B/lane: HW semantics = wave-uniform LDS base +
// lane*16B dest, per-lane GLOBAL source (m97/m104).  Fallback emulates the
// exact same layout if the builtin is unavailable (R10 audit: bit-identical
// dest map, so correctness is invariant to builtin availability).
// NOTE (R7): global pointer param of the builtin is NON-const (clang
// prototype) -- cast must drop const or compile fails.
#if defined(__has_builtin)
#if __has_builtin(__builtin_amdgcn_global_load_lds)
#define HAVE_GLDS 1
#endif
#endif

#ifdef HAVE_GLDS
static __device__ __forceinline__ void glds16(const void* g, void* l) {
  __builtin_amdgcn_global_load_lds(
      (__attribute__((address_space(1))) void*)g,
      (__attribute__((address_space(3))) void*)l, 16, 0, 0);
}
#else
static __device__ __forceinline__ void glds16(const void* g, void* l) {
  u32x4 v = *(const u32x4*)g;
  ((u32x4*)l)[threadIdx.x & 63] = v;   // base + lane*16B, same final layout
}
#endif

// ---------------------------------------------------------------------------
// Kernel 1: featT[n][k] = bf16(feat[k][n])  (tiled transpose)  +  Wb = bf16(W)
// R6: transposed featT stores vectorized to short4 (8 B/lane; was 2 B/lane).
// Write map audited: (t>>4, t&15) bijective over 16 rows x 16 k-chunks,
// x4 passes covers all 64 rows; every element written exactly once.
// ---------------------------------------------------------------------------
__global__ __launch_bounds__(256)
void k_prep(const float* __restrict__ feat, const float* __restrict__ W,
            short* __restrict__ featT, short* __restrict__ Wb) {
  int b = blockIdx.x;
  int t = threadIdx.x;
  if (b < 1024) {
    __shared__ short tile[64][65];   // +1 pad: conflict-free transposed reads
    int tk = b >> 2, tn = b & 3;
    int k0 = tk * 64, n0 = tn * 64;
    int c = t & 63, rb = t >> 6;
#pragma unroll
    for (int i = 0; i < 16; ++i) {
      int r = rb + i * 4;
      tile[r][c] = f2bf(feat[(k0 + r) * D_ + n0 + c]);
    }
    __syncthreads();
    int c4 = (t & 15) * 4;           // k-chunk start (0..60)
    int rw = t >> 4;                 // n-row within pass (0..15)
#pragma unroll
    for (int i = 0; i < 4; ++i) {
      int r = rw + i * 16;           // n-row 0..63
      short4_t o;
      o[0] = tile[c4 + 0][r];
      o[1] = tile[c4 + 1][r];
      o[2] = tile[c4 + 2][r];
      o[3] = tile[c4 + 3][r];
      *(short4_t*)&featT[(long)(n0 + r) * N_ + k0 + c4] = o;
    }
  } else {
    int base = (b - 1024) * 256 + t;   // 32 blocks cover 256*512 = 131072 elems
#pragma unroll
    for (int i = 0; i < 16; ++i) {
      int idx = base + i * 8192;
      Wb[idx] = f2bf(W[idx]);
    }
  }
}

// ---------------------------------------------------------------------------
// Kernel 2: partial[s] = adj[:, ks] @ feat[ks, :]  (bf16 MFMA, fp32 acc)
//           degp[s][m] = rowsum(adj[m, ks])  -- fused into adj staging
//
//  * Bt (featT) staged via global_load_lds, 16B/lane: 8 instrs/wave/tile,
//    no register round-trip, no ds_writes.  T2 swizzle moved to the GLOBAL
//    source per m173/rule#21: lane source column fc' = fc ^ (fr&7) (valid
//    for all sub-passes since rows step by 32 == 0 mod 8), LDS linear ->
//    LDS[r][c] = global[r][c^(r&7)], matching the existing swizzled read.
//    R8 audit: dest row i*32+w*8+(l>>3) == source row i*32+fr; dest chunk
//    l&7 == fc; read row&7 == ml&7 == sw de-swizzles correctly.
//  * At (adj) reg-staged (fp32->bf16 convert + rowsum), swizzled ds_write.
//  * T1 bijective XCD swizzle (512 % 8 == 0): one featT panel per XCD L2.
//  * Double-buffered, one barrier per K-step.  glds(t+1) issued at top of
//    each iter (its buffer's last read ended at the pre-previous barrier);
//    adj loads distance-1.5-2 in two static reg sets (rule #20).  The
//    barrier's vmcnt(0) drain is REQUIRED for glds LDS-visibility; adj
//    loads complete at the same drain -> stages never wait.
//    Schedule trace: glds tiles 0..127 once each (pro 0, loop 1..126,
//    epi 127); adj loads 0..127 once each; stages/computes 0..127 once
//    each; buffer parity == tile parity throughout; no OOB.
// ---------------------------------------------------------------------------
__global__ __launch_bounds__(256, 2)
void k_main(const float* __restrict__ adj, const short* __restrict__ featT,
            float* __restrict__ part, float* __restrict__ degp) {
  __shared__ short At[2][BM * BK];   // 2 x 8 KiB, swizzled
  __shared__ short Bt[2][D_ * BK];   // 2 x 32 KiB, swizzled content, linear fill
  int tid = threadIdx.x;
  int w = tid >> 6, lane = tid & 63;
  int q = lane >> 4, ml = lane & 15;
  int sw = ml & 7;                   // read-side swizzle key (row&7 for all frag rows)

  // T1: bijective chunked XCD swizzle (nwg=512, 512%8==0 -> simple form OK)
  int bid = blockIdx.x;
  int bsw = ((bid & 7) << 6) | (bid >> 3);
  int s = bsw >> 8;                  // K-split 0..1
  int m0 = (bsw & 255) * BM;         // M-block 0..255
  long kbase = (long)s * KPER;

  f32x4 acc[4][4];
#pragma unroll
  for (int i = 0; i < 4; ++i)
#pragma unroll
    for (int j = 0; j < 4; ++j)
#pragma unroll
      for (int r = 0; r < 4; ++r) acc[i][j][r] = 0.f;

  int ar = tid >> 2;                 // adj row 0..63 (4 threads/row)
  int aj = tid & 3;                  // which 16-elem slice of the row
  const float* adjp = adj + (long)(m0 + ar) * N_ + kbase + aj * 16;
  int fr = tid >> 3, fc = tid & 7;   // featT staging thread map (8 thr/row)
  // pre-swizzled per-lane global source column (rule #21: source perm == read perm)
  const short* featp = featT + (long)fr * N_ + kbase + ((fc ^ (fr & 7)) * 8);

  // swizzled At write offsets (element units; chunks are 8 bf16 = 16 B)
  const int atw0 = ar * BK + (((aj << 1) | 0) ^ (ar & 7)) * 8;
  const int atw1 = ar * BK + (((aj << 1) | 1) ^ (ar & 7)) * 8;

  float rowsum = 0.f;

  // two static adj register sets (distance-2 prefetch, rule #20)
  f32x4 vA0, vA1, vA2, vA3, vB0, vB1, vB2, vB3;

  auto loadA = [&]() {                     // 4 vmem ops, no waits
    vA0 = *(const f32x4*)(adjp);
    vA1 = *(const f32x4*)(adjp + 4);
    vA2 = *(const f32x4*)(adjp + 8);
    vA3 = *(const f32x4*)(adjp + 12);
    adjp += BK;
  };
  auto loadB = [&]() {
    vB0 = *(const f32x4*)(adjp);
    vB1 = *(const f32x4*)(adjp + 4);
    vB2 = *(const f32x4*)(adjp + 8);
    vB3 = *(const f32x4*)(adjp + 12);
    adjp += BK;
  };

  auto gldsB = [&](int buf) {              // featT tile -> Bt[buf], 8 instrs/wave
#pragma unroll
    for (int i = 0; i < 8; ++i)
      glds16(featp + (long)i * 32 * N_, &Bt[buf][(i * 32 + (w << 3)) * BK]);
    featp += BK;
  };

  auto stageA = [&](int buf) {             // consumes adj set A
    rowsum += vA0[0] + vA0[1] + vA0[2] + vA0[3] + vA1[0] + vA1[1] + vA1[2] + vA1[3] +
              vA2[0] + vA2[1] + vA2[2] + vA2[3] + vA3[0] + vA3[1] + vA3[2] + vA3[3];
    short8_t pa, pb;
    pa[0] = f2bf(vA0[0]); pa[1] = f2bf(vA0[1]); pa[2] = f2bf(vA0[2]); pa[3] = f2bf(vA0[3]);
    pa[4] = f2bf(vA1[0]); pa[5] = f2bf(vA1[1]); pa[6] = f2bf(vA1[2]); pa[7] = f2bf(vA1[3]);
    pb[0] = f2bf(vA2[0]); pb[1] = f2bf(vA2[1]); pb[2] = f2bf(vA2[2]); pb[3] = f2bf(vA2[3]);
    pb[4] = f2bf(vA3[0]); pb[5] = f2bf(vA3[1]); pb[6] = f2bf(vA3[2]); pb[7] = f2bf(vA3[3]);
    *(short8_t*)&At[buf][atw0] = pa;
    *(short8_t*)&At[buf][atw1] = pb;
  };
  auto stageB = [&](int buf) {             // consumes adj set B
    rowsum += vB0[0] + vB0[1] + vB0[2] + vB0[3] + vB1[0] + vB1[1] + vB1[2] + vB1[3] +
              vB2[0] + vB2[1] + vB2[2] + vB2[3] + vB3[0] + vB3[1] + vB3[2] + vB3[3];
    short8_t pa, pb;
    pa[0] = f2bf(vB0[0]); pa[1] = f2bf(vB0[1]); pa[2] = f2bf(vB0[2]); pa[3] = f2bf(vB0[3]);
    pa[4] = f2bf(vB1[0]); pa[5] = f2bf(vB1[1]); pa[6] = f2bf(vB1[2]); pa[7] = f2bf(vB1[3]);
    pb[0] = f2bf(vB2[0]); pb[1] = f2bf(vB2[1]); pb[2] = f2bf(vB2[2]); pb[3] = f2bf(vB2[3]);
    pb[4] = f2bf(vB3[0]); pb[5] = f2bf(vB3[1]); pb[6] = f2bf(vB3[2]); pb[7] = f2bf(vB3[3]);
    *(short8_t*)&At[buf][atw0] = pa;
    *(short8_t*)&At[buf][atw1] = pb;
  };

  auto compute_tile = [&](int buf) {       // 16 swizzled ds_read_b128 + 32 MFMA
#pragma unroll
    for (int ks = 0; ks < 2; ++ks) {
      short8_t a[4], bb[4];
#pragma unroll
      for (int i = 0; i < 4; ++i)
        a[i] = *(const short8_t*)
            &At[buf][(i * 16 + ml) * BK + (((ks << 2) | q) ^ sw) * 8];
#pragma unroll
      for (int j = 0; j < 4; ++j)
        bb[j] = *(const short8_t*)
            &Bt[buf][(w * 64 + j * 16 + ml) * BK + (((ks << 2) | q) ^ sw) * 8];
#pragma unroll
      for (int i = 0; i < 4; ++i)
#pragma unroll
        for (int j = 0; j < 4; ++j)
          acc[i][j] = __builtin_amdgcn_mfma_f32_16x16x32_bf16(a[i], bb[j], acc[i][j], 0, 0, 0);
    }
  };

  // prologue: tile 0 fully staged; tile 1 adj in flight
  gldsB(0);                // tile 0 -> Bt[0]
  loadA();                 // tile 0 adj
  loadB();                 // tile 1 adj
  stageA(0);               // tile 0 -> At[0]
  __syncthreads();         // drains glds + adj loads

  // steady state: 63 unrolled pairs; one barrier per K-step
  for (int t = 0; t + 3 < NT; t += 2) {
    gldsB(1);              // tile t+1 -> Bt[1]  (last read: pre-previous barrier)
    loadA();               // tile t+2 adj
    compute_tile(0);       // tile t
    stageB(1);             // tile t+1 adj -> At[1]
    __syncthreads();
    gldsB(0);              // tile t+2 -> Bt[0]
    loadB();               // tile t+3 adj
    compute_tile(1);       // tile t+1
    stageA(0);             // tile t+2 adj -> At[0]
    __syncthreads();
  }
  // here t==126: Bt[0]/At[0] hold tile 126; adj set B holds tile 127
  gldsB(1);                // tile 127 -> Bt[1]
  compute_tile(0);         // tile 126
  stageB(1);               // tile 127 adj -> At[1]
  __syncthreads();
  compute_tile(1);         // tile 127

  // degree partial: reduce the 4 threads sharing a row (adjacent lanes)
  float rs = rowsum;
  rs += __shfl_xor(rs, 1);
  rs += __shfl_xor(rs, 2);
  if ((tid & 3) == 0) degp[s * N_ + m0 + ar] = rs;

  // store fp32 partial (C/D layout: col=lane&15, row=quad*4+reg  [m89-verified])
  float* pp = part + (long)s * N_ * D_ + (long)m0 * D_ + w * 64;
#pragma unroll
  for (int i = 0; i < 4; ++i)
#pragma unroll
    for (int j = 0; j < 4; ++j)
#pragma unroll
      for (int r = 0; r < 4; ++r)
        pp[(i * 16 + q * 4 + r) * D_ + j * 16 + ml] = acc[i][j][r];
}

// ---------------------------------------------------------------------------
// Kernel 3: out[16384][256] = [feat | neigh] @ W.T   (K=512, bf16 MFMA)
// iters 0-3 stage A from fp32 feat (convert); iters 4-7 FUSE the old
// k_combine: A = bf16((part0 + part1) * inv), inv = 1/(deg0+deg1+1).
// Same audited T2 swizzle as k_main on both LDS tiles (reg-staged).
// ---------------------------------------------------------------------------
__global__ __launch_bounds__(256, 2)
void k_out(const float* __restrict__ feat, const float* __restrict__ part,
           const float* __restrict__ degp, const short* __restrict__ Wb,
           float* __restrict__ out) {
  __shared__ short At[BM * BK];
  __shared__ short Bt[D_ * BK];
  int tid = threadIdx.x;
  int w = tid >> 6, lane = tid & 63;
  int q = lane >> 4, ml = lane & 15;
  int sw = ml & 7;
  int m0 = blockIdx.x * BM;

  f32x4 acc[4][4];
#pragma unroll
  for (int i = 0; i < 4; ++i)
#pragma unroll
    for (int j = 0; j < 4; ++j)
#pragma unroll
      for (int r = 0; r < 4; ++r) acc[i][j][r] = 0.f;

  int ar = tid >> 2, aj = tid & 3, ac = aj * 16;
  int fr = tid >> 3, fc = tid & 7;
  const int atw0 = ar * BK + (((aj << 1) | 0) ^ (ar & 7)) * 8;
  const int atw1 = ar * BK + (((aj << 1) | 1) ^ (ar & 7)) * 8;
  const int btc  = (fc ^ (fr & 7)) * 8;

  // per-row normalization (row m0+ar fixed per thread; hoisted)
  const float inv = 1.0f / (degp[m0 + ar] + degp[N_ + m0 + ar] + 1.0f);

  for (int it = 0; it < 8; ++it) {
    int k0 = it * BK;
    short8_t pa, pb;
    if (it < 4) {
      const float* src = feat + (long)(m0 + ar) * D_ + k0 + ac;
      f32x4 v0 = *(const f32x4*)(src);
      f32x4 v1 = *(const f32x4*)(src + 4);
      f32x4 v2 = *(const f32x4*)(src + 8);
      f32x4 v3 = *(const f32x4*)(src + 12);
      pa[0] = f2bf(v0[0]); pa[1] = f2bf(v0[1]); pa[2] = f2bf(v0[2]); pa[3] = f2bf(v0[3]);
      pa[4] = f2bf(v1[0]); pa[5] = f2bf(v1[1]); pa[6] = f2bf(v1[2]); pa[7] = f2bf(v1[3]);
      pb[0] = f2bf(v2[0]); pb[1] = f2bf(v2[1]); pb[2] = f2bf(v2[2]); pb[3] = f2bf(v2[3]);
      pb[4] = f2bf(v3[0]); pb[5] = f2bf(v3[1]); pb[6] = f2bf(v3[2]); pb[7] = f2bf(v3[3]);
    } else {
      const float* s0 = part + (long)(m0 + ar) * D_ + (k0 - 256) + ac;
      const float* s1 = s0 + (long)N_ * D_;
      f32x4 a0 = *(const f32x4*)(s0);
      f32x4 a1 = *(const f32x4*)(s0 + 4);
      f32x4 a2 = *(const f32x4*)(s0 + 8);
      f32x4 a3 = *(const f32x4*)(s0 + 12);
      f32x4 b0 = *(const f32x4*)(s1);
      f32x4 b1 = *(const f32x4*)(s1 + 4);
      f32x4 b2 = *(const f32x4*)(s1 + 8);
      f32x4 b3 = *(const f32x4*)(s1 + 12);
#pragma unroll
      for (int r = 0; r < 4; ++r) {
        pa[r]     = f2bf((a0[r] + b0[r]) * inv);
        pa[r + 4] = f2bf((a1[r] + b1[r]) * inv);
        pb[r]     = f2bf((a2[r] + b2[r]) * inv);
        pb[r + 4] = f2bf((a3[r] + b3[r]) * inv);
      }
    }
    u32x4 bv[8];
#pragma unroll
    for (int i = 0; i < 8; ++i)
      bv[i] = *(const u32x4*)(Wb + (i * 32 + fr) * 512 + k0 + fc * 8);

    *(short8_t*)&At[atw0] = pa;
    *(short8_t*)&At[atw1] = pb;
#pragma unroll
    for (int i = 0; i < 8; ++i)
      *(u32x4*)&Bt[(i * 32 + fr) * BK + btc] = bv[i];

    __syncthreads();

#pragma unroll
    for (int ks = 0; ks < 2; ++ks) {
      short8_t a[4], bb[4];
#pragma unroll
      for (int i = 0; i < 4; ++i)
        a[i] = *(const short8_t*)
            &At[(i * 16 + ml) * BK + (((ks << 2) | q) ^ sw) * 8];
#pragma unroll
      for (int j = 0; j < 4; ++j)
        bb[j] = *(const short8_t*)
            &Bt[(w * 64 + j * 16 + ml) * BK + (((ks << 2) | q) ^ sw) * 8];
#pragma unroll
      for (int i = 0; i < 4; ++i)
#pragma unroll
        for (int j = 0; j < 4; ++j)
          acc[i][j] = __builtin_amdgcn_mfma_f32_16x16x32_bf16(a[i], bb[j], acc[i][j], 0, 0, 0);
    }
    __syncthreads();
  }

  float* op = out + (long)m0 * D_ + w * 64;
#pragma unroll
  for (int i = 0; i < 4; ++i)
#pragma unroll
    for (int j = 0; j < 4; ++j)
#pragma unroll
      for (int r = 0; r < 4; ++r)
        op[(i * 16 + q * 4 + r) * D_ + j * 16 + ml] = acc[i][j][r];
}

// ---------------------------------------------------------------------------
extern "C" void kernel_launch(void* const* d_in, const int* in_sizes, int n_in,
                              void* d_out, int out_size, void* d_ws, size_t ws_size,
                              hipStream_t stream) {
  const float* feat = (const float*)d_in[0];   // [16384][256]
  const float* adj  = (const float*)d_in[1];   // [16384][16384]
  const float* W    = (const float*)d_in[2];   // [256][512]
  float* out = (float*)d_out;                  // [16384][256]

  char* ws = (char*)d_ws;
  short* featT = (short*)(ws);                 // [256][16384] bf16  : 8 MiB
  short* Wb    = (short*)(ws + (8l << 20));    // [256][512]  bf16  : 256 KiB
  float* part  = (float*)(ws + (17l << 20));   // [2][16384][256]   : 32 MiB
  float* degp  = (float*)(ws + (49l << 20));   // [2][16384]        : 128 KiB
  // total ws use: ~49.2 MiB

  k_prep<<<dim3(1024 + 32), 256, 0, stream>>>(feat, W, featT, Wb);
  k_main<<<dim3(N_ / BM * KSPLIT), 256, 0, stream>>>(adj, featT, part, degp);
  k_out<<<dim3(N_ / BM), 256, 0, stream>>>(feat, part, degp, Wb, out);
}